// Round 7
// baseline (354.859 us; speedup 1.0000x reference)
//
#include <hip/hip_runtime.h>

typedef unsigned short u16;
typedef unsigned int u32;
typedef __attribute__((ext_vector_type(8))) short short8;
typedef __attribute__((ext_vector_type(4))) float floatx4;

#define HEADS 8
#define DIM 512          // K for both GEMMs
#define HH 96
#define WW 96
#define NPIX 9216
#define M_TOT 36864
#define N_QKV 1536
#define SCALE 0.125f

__device__ __forceinline__ float b2f(u16 v){
    union{float f;u32 u;}x; x.u=((u32)v)<<16; return x.f;
}
__device__ __forceinline__ u16 f2b(float f){
    union{float f;u32 u;}x; x.f=f;
    u32 u=x.u + 0x7fffu + ((x.u>>16)&1u);
    return (u16)(u>>16);
}
// packed f32x2 -> bf16x2 (RNE, matches f2b bit-for-bit); no builtin on gfx950
__device__ __forceinline__ u32 pack2(float a,float b){
    u32 r; asm("v_cvt_pk_bf16_f32 %0, %1, %2" : "=v"(r) : "v"(a), "v"(b));
    return r;
}
__device__ __forceinline__ short8 mk8(u32 a,u32 b,u32 c,u32 d){
    union{u32 u[4]; short8 v;} x; x.u[0]=a; x.u[1]=b; x.u[2]=c; x.u[3]=d; return x.v;
}

// async global->LDS, 16 B per lane; lds dest = wave-uniform base + lane*16
__device__ __forceinline__ void gload16(const u16* g, u16* l){
    __builtin_amdgcn_global_load_lds(
        (const __attribute__((address_space(1))) u32*)g,
        (__attribute__((address_space(3))) u32*)l, 16, 0, 0);
}

// ---------------------------------------------------------------------------
// dtype detector (bf16 vs fp32 inputs)
// ---------------------------------------------------------------------------
__global__ void detect_dtype(const u16* __restrict__ wq, int* __restrict__ flag){
    __shared__ int cnt;
    if (threadIdx.x==0) cnt=0;
    __syncthreads();
    u16 u = wq[2*threadIdx.x];
    int e = (u>>7)&0xff;
    if (e>=100 && e<=128) atomicAdd(&cnt,1);
    __syncthreads();
    if (threadIdx.x==0) *flag = (cnt>128)?1:0;
}

// ---------------------------------------------------------------------------
// Weights -> bf16 (layout unchanged, [n][k] k-contiguous)
// ---------------------------------------------------------------------------
__global__ __launch_bounds__(256)
void convert_w(const void* __restrict__ wq, const void* __restrict__ wo,
               const int* __restrict__ flag, u16* __restrict__ wqb, u16* __restrict__ wob){
    const int isb = *flag;
    int i = blockIdx.x*256 + threadIdx.x;
    const int nq = N_QKV*DIM;                 // 786432
    if (i < nq){
        wqb[i] = isb ? ((const u16*)wq)[i] : f2b(((const float*)wq)[i]);
    } else {
        int j = i - nq;                       // < 262144
        wob[j] = isb ? ((const u16*)wo)[j] : f2b(((const float*)wo)[j]);
    }
}

// ---------------------------------------------------------------------------
// x [b][c][pix] (fp32 or bf16) -> xb [b*9216+pix][c] bf16   (transpose)
// ---------------------------------------------------------------------------
__global__ __launch_bounds__(256)
void convert_x(const void* __restrict__ xv, const int* __restrict__ flag,
               u16* __restrict__ xb){
    __shared__ u16 tile[64][65];
    const int isb = *flag;
    const int p0 = blockIdx.x*64, c0 = blockIdx.y*64, b = blockIdx.z;
    const int t = threadIdx.x;
    const int pl = t&63, c4 = t>>6;
    const float* x32 = (const float*)xv;
    const u16*   x16 = (const u16*)xv;
    size_t src = ((size_t)b*DIM + c0 + c4)*NPIX + p0 + pl;
    #pragma unroll
    for (int i=0;i<16;i++){
        int cl = c4 + i*4;
        size_t s = src + (size_t)i*4*NPIX;
        tile[cl][pl] = isb ? x16[s] : f2b(x32[s]);
    }
    __syncthreads();
    const int cu = t&31, r8 = t>>5;
    u32* xb32 = (u32*)xb;
    #pragma unroll
    for (int i=0;i<8;i++){
        int pr = r8 + i*8;
        u32 v = (u32)tile[2*cu][pr] | ((u32)tile[2*cu+1][pr]<<16);
        xb32[((size_t)b*NPIX + p0 + pr)*(DIM/2) + (c0>>1) + cu] = v;
    }
}

// ---------------------------------------------------------------------------
// MFMA GEMM 1: 128x128 tile, BK=64, 4 waves (2M x 2N), double-buffered LDS,
// counted vmcnt(2), 64 KB LDS -> TWO blocks/CU: one block's epilogue/
// prologue/phase bubbles overlap the other's main loop (the 1-block/CU
// variants all plateaued 89-96 us regardless of schedule).
// Epilogues write block-contiguous chunk images (R4-verified layouts):
//   qkt[(bh*96+row)] = 24KB (12 Q-chunks then 12 K-chunks of 1KB)
//   vtt[(bh*96+row)] = 12KB (12 chunks: (dt*3+jt)*512)
// Wave n-span 64 == one head's d range for Q, K and V.
// Grid 3456 = 8 XCDs x 432; 12 consecutive slots share one A-panel per XCD.
// ---------------------------------------------------------------------------
__global__ __launch_bounds__(256, 2)
void gemm_qkv(const u16* __restrict__ A, const u16* __restrict__ B,
              u16* __restrict__ qkt, u16* __restrict__ vtt){
    __shared__ __align__(16) union ShMem {
        u16 tiles[32768];            // 2 bufs x (A 8192 + B 8192) u16 = 64 KiB
        float ct[4][16][68];         // per-wave epilogue transpose
    } sh;
    u16* lds = sh.tiles;
    const int id = blockIdx.x;
    const int xcd = id & 7, slot = id >> 3;        // 3456 = 8 x 432
    const int q12 = slot/12;
    const int by = xcd*36 + q12;                   // same A-panel -> same XCD
    const int bx = slot - q12*12;
    const int t = threadIdx.x;
    const int w = t>>6, l = t&63, lr = l&15, lq = l>>4;
    const int wm = w>>1, wn = w&1;                 // wave = 64(M) x 64(N)
    const int m0 = by*128, n0 = bx*128;
    const u16* gA = A + (size_t)(m0 + w*16 + lr)*DIM + lq*8;
    const u16* gB = B + (size_t)(n0 + w*16 + lr)*DIM + lq*8;

#define STG_A(h, ko, bb) do { \
        const u16* _g = gA + (size_t)(h)*32768 + (ko); \
        u16* _l = lds + (bb)*16384 + ((h)*4 + w)*1024; \
        gload16(_g,      _l); \
        gload16(_g + 32, _l + 512); \
    } while(0)
#define STG_B(h, ko, bb) do { \
        const u16* _g = gB + (size_t)(h)*32768 + (ko); \
        u16* _l = lds + (bb)*16384 + 8192 + ((h)*4 + w)*1024; \
        gload16(_g,      _l); \
        gload16(_g + 32, _l + 512); \
    } while(0)

    floatx4 acc[4][4] = {};
    STG_A(0,0,0); STG_A(1,0,0); STG_B(0,0,0); STG_B(1,0,0);

    #pragma unroll 1
    for (int kt=0; kt<8; ++kt){
        const int cur = kt&1, nxt = cur^1;
        const int ko = (kt+1)*64;
        if (kt < 7){
            STG_A(0, ko, nxt);
            asm volatile("s_waitcnt vmcnt(2)" ::: "memory");
        } else {
            asm volatile("s_waitcnt vmcnt(0)" ::: "memory");
        }
        __builtin_amdgcn_s_barrier();
        asm volatile("" ::: "memory");
        const u16* bA = lds + cur*16384 +        wm*4096 + l*8;
        const u16* bB = lds + cur*16384 + 8192 + wn*4096 + l*8;
        short8 af[4][2], bf[2][2];
        // ---- phase 0: read A + B-lo; stage A1; MFMA n-tiles 0,1
        #pragma unroll
        for (int mi=0;mi<4;mi++){
            af[mi][0] = *(const short8*)(bA + mi*1024);
            af[mi][1] = *(const short8*)(bA + mi*1024 + 512);
        }
        #pragma unroll
        for (int ni=0;ni<2;ni++){
            bf[ni][0] = *(const short8*)(bB + ni*1024);
            bf[ni][1] = *(const short8*)(bB + ni*1024 + 512);
        }
        if (kt < 7) STG_A(1, ko, nxt);
        asm volatile("" ::: "memory");
        __builtin_amdgcn_s_barrier();
        __builtin_amdgcn_sched_barrier(0);
        __builtin_amdgcn_s_setprio(1);
        #pragma unroll
        for (int mi=0;mi<4;mi++)
            #pragma unroll
            for (int ni=0;ni<2;ni++){
                acc[mi][ni] = __builtin_amdgcn_mfma_f32_16x16x32_bf16(af[mi][0], bf[ni][0], acc[mi][ni], 0,0,0);
                acc[mi][ni] = __builtin_amdgcn_mfma_f32_16x16x32_bf16(af[mi][1], bf[ni][1], acc[mi][ni], 0,0,0);
            }
        __builtin_amdgcn_s_setprio(0);
        __builtin_amdgcn_sched_barrier(0);
        __builtin_amdgcn_s_barrier();
        // ---- phase 1: read B-hi; stage B0+B1; MFMA n-tiles 2,3
        #pragma unroll
        for (int ni=0;ni<2;ni++){
            bf[ni][0] = *(const short8*)(bB + (2+ni)*1024);
            bf[ni][1] = *(const short8*)(bB + (2+ni)*1024 + 512);
        }
        if (kt < 7){ STG_B(0, ko, nxt); STG_B(1, ko, nxt); }
        asm volatile("" ::: "memory");
        __builtin_amdgcn_s_barrier();
        __builtin_amdgcn_sched_barrier(0);
        __builtin_amdgcn_s_setprio(1);
        #pragma unroll
        for (int mi=0;mi<4;mi++)
            #pragma unroll
            for (int ni=0;ni<2;ni++){
                acc[mi][2+ni] = __builtin_amdgcn_mfma_f32_16x16x32_bf16(af[mi][0], bf[ni][0], acc[mi][2+ni], 0,0,0);
                acc[mi][2+ni] = __builtin_amdgcn_mfma_f32_16x16x32_bf16(af[mi][1], bf[ni][1], acc[mi][2+ni], 0,0,0);
            }
        __builtin_amdgcn_s_setprio(0);
        __builtin_amdgcn_sched_barrier(0);
        asm volatile("" ::: "memory");
        __builtin_amdgcn_s_barrier();
        asm volatile("" ::: "memory");
    }
#undef STG_A
#undef STG_B
    const int bat   = m0 / NPIX;
    const int p0img = (m0 - bat*NPIX) + wm*64;     // pix offset in image
    float (*ct)[68] = sh.ct[w];
    if (bx < 8){
        // Q (bx<4) / K (bx 4..7) epilogue -> qkt chunks
        const int nbase = n0 + wn*64;              // 0..1023
        const int isK   = (nbase >= 512);
        const int head  = (nbase - (isK ? 512 : 0)) >> 6;
        const int kqoff = isK ? 6144 : 0;
        const size_t blk0 = (size_t)(bat*8 + head)*96;
        #pragma unroll
        for (int mi=0;mi<4;mi++){
            #pragma unroll
            for (int ni=0;ni<4;ni++)
                #pragma unroll
                for (int r=0;r<4;r++)
                    ct[lq*4+r][ni*16+lr] = acc[mi][ni][r];   // [pix16][d64]
            int pv  = (p0img + mi*16) >> 4;        // 16-pix tile index
            int row = pv/6, mt = pv - row*6;
            u16* dst = qkt + (blk0 + row)*12288 + kqoff + mt*1024 + l*8;
            #pragma unroll
            for (int ks=0;ks<2;ks++){
                const float* cp = &ct[l&15][ks*32 + (l>>4)*8];
                float4 v0 = *(const float4*)(cp);
                float4 v1 = *(const float4*)(cp+4);
                uint4 s;
                s.x=pack2(v0.x,v0.y); s.y=pack2(v0.z,v0.w);
                s.z=pack2(v1.x,v1.y); s.w=pack2(v1.z,v1.w);
                *((uint4*)(dst + ks*512)) = s;     // 1KB-contiguous per store
            }
        }
    } else {
        // V epilogue -> vtt chunks
        const int head = ((n0 - 1024) + wn*64) >> 6;
        const size_t blk0 = (size_t)(bat*8 + head)*96;
        for (int ni=0; ni<4; ni++){                // ni = d-tile dt
            #pragma unroll
            for (int mi=0;mi<4;mi++)
                #pragma unroll
                for (int r=0;r<4;r++)
                    ct[lr][mi*16 + lq*4 + r] = acc[mi][ni][r];  // [d16][pix64]
            #pragma unroll
            for (int cc=0;cc<2;cc++){
                int p32 = (p0img + cc*32) >> 5;    // 32-pix chunk index
                int row = p32/3, jt = p32 - row*3;
                const float* cp = &ct[l&15][cc*32 + (l>>4)*8];
                float4 v0 = *(const float4*)(cp);
                float4 v1 = *(const float4*)(cp+4);
                uint4 s;
                s.x=pack2(v0.x,v0.y); s.y=pack2(v0.z,v0.w);
                s.z=pack2(v1.x,v1.y); s.w=pack2(v1.z,v1.w);
                *((uint4*)(vtt + (blk0 + row)*6144 + (ni*3 + jt)*512 + l*8)) = s;
            }
        }
    }
}

// ---------------------------------------------------------------------------
// Kernel 2 (R5-verified): attention, ONE WAVE per (bh,row,qt). Zero LDS,
// zero barriers. 18432 waves, 4608 blocks, XCD-grouped for L2 reuse.
// ---------------------------------------------------------------------------
__global__ __launch_bounds__(256)
void attn_kernel(const u16* __restrict__ qkt, const u16* __restrict__ vtt,
                 u16* __restrict__ attno){
    const int t = threadIdx.x;
    const int w = t>>6, l = t&63, lr = l&15, lq = l>>4;
    const int id  = blockIdx.x;
    const int bid = (id&7)*576 + (id>>3);      // bijective: 4608 = 8*576
    const int widx = bid*4 + w;                // 18432 = 3072 rows * 6 qt
    const int qt   = widx % 6;
    const int rowu = widx / 6;                 // (bat*8+head)*96 + row
    const int row  = rowu % HH;
    const int bh   = rowu / HH;
    const int head = bh & 7, bat = bh >> 3;
    const u16* qkb = qkt + (size_t)rowu*12288;
    const u16* vb  = vtt + (size_t)rowu*6144;
    short8 qf0 = *(const short8*)(qkb + (qt*2+0)*512 + l*8);
    short8 qf1 = *(const short8*)(qkb + (qt*2+1)*512 + l*8);
    floatx4 s[6];
    #pragma unroll
    for (int jt=0;jt<6;jt++){
        short8 k0 = *(const short8*)(qkb + 6144 + (jt*2+0)*512 + l*8);
        short8 k1 = *(const short8*)(qkb + 6144 + (jt*2+1)*512 + l*8);
        floatx4 a = {};
        a = __builtin_amdgcn_mfma_f32_16x16x32_bf16(k0, qf0, a, 0,0,0);
        a = __builtin_amdgcn_mfma_f32_16x16x32_bf16(k1, qf1, a, 0,0,0);
        s[jt] = a;
    }
    float m = -1e30f;
    #pragma unroll
    for (int jt=0;jt<6;jt++)
        #pragma unroll
        for (int r=0;r<4;r++){ s[jt][r] *= SCALE; m = fmaxf(m, s[jt][r]); }
    m = fmaxf(m, __shfl_xor(m, 16));
    m = fmaxf(m, __shfl_xor(m, 32));
    float sum = 0.f;
    u32 pk0[6], pk1[6];
    #pragma unroll
    for (int jt=0;jt<6;jt++){
        float e0 = __expf(s[jt][0]-m), e1 = __expf(s[jt][1]-m);
        float e2 = __expf(s[jt][2]-m), e3 = __expf(s[jt][3]-m);
        sum += e0+e1+e2+e3;
        pk0[jt] = pack2(e0,e1);
        pk1[jt] = pack2(e2,e3);
    }
    sum += __shfl_xor(sum, 16);
    sum += __shfl_xor(sum, 32);
    const float rinv = 1.f/sum;
    const int srcA = lr + ((lq&1)<<5);
    const int srcB = srcA + 16;
    const int hi   = lq>>1;
    short8 pf[3];
    #pragma unroll
    for (int kb=0;kb<3;kb++){
        u32 x0=__shfl(pk0[kb*2],srcA), y0=__shfl(pk0[kb*2+1],srcA);
        u32 x1=__shfl(pk1[kb*2],srcA), y1=__shfl(pk1[kb*2+1],srcA);
        u32 x2=__shfl(pk0[kb*2],srcB), y2=__shfl(pk0[kb*2+1],srcB);
        u32 x3=__shfl(pk1[kb*2],srcB), y3=__shfl(pk1[kb*2+1],srcB);
        pf[kb] = mk8(hi?y0:x0, hi?y1:x1, hi?y2:x2, hi?y3:x3);
    }
    floatx4 o[4] = {};
    #pragma unroll
    for (int kb=0;kb<3;kb++){
        #pragma unroll
        for (int dt=0;dt<4;dt++){
            short8 vf = *(const short8*)(vb + (dt*3+kb)*512 + l*8);
            o[dt] = __builtin_amdgcn_mfma_f32_16x16x32_bf16(vf, pf[kb], o[dt], 0,0,0);
        }
    }
    const size_t pixrow = (size_t)bat*NPIX + row*WW + qt*16;
    u16* ob = attno + (pixrow + lr)*512 + head*64 + lq*4;
    #pragma unroll
    for (int dt=0;dt<4;dt++){
        uint2 st;
        st.x = pack2(o[dt][0]*rinv, o[dt][1]*rinv);
        st.y = pack2(o[dt][2]*rinv, o[dt][3]*rinv);
        *(uint2*)(ob + dt*16) = st;
    }
}

// ---------------------------------------------------------------------------
// MFMA GEMM 2 (R5-verified): out = attn_ws * wob^T + bias. 128x128 tile,
// BK=64, 4 waves, 64 KB LDS -> 2 blocks/CU. Grid 1152 = 8 x 144.
// ---------------------------------------------------------------------------
__global__ __launch_bounds__(256, 2)
void gemm_out(const u16* __restrict__ A, const u16* __restrict__ B,
              const void* __restrict__ bias, const int* __restrict__ flag,
              void* __restrict__ outv){
    __shared__ __align__(16) union ShMem {
        u16 tiles[32768];            // 2 bufs x (A 8192 + B 8192) u16 = 64 KiB
        float ct[4][16][68];
    } sh;
    u16* lds = sh.tiles;
    const int id = blockIdx.x;
    const int xcd = id & 7, slot = id >> 3;        // 1152 = 8 x 144
    const int by = xcd*36 + (slot>>2);
    const int bx = slot & 3;
    const int t = threadIdx.x;
    const int w = t>>6, l = t&63, lr = l&15, lq = l>>4;
    const int wm = w>>1, wn = w&1;                 // wave = 64(M) x 64(N)
    const int m0 = by*128, n0 = bx*128;
    const u16* gA = A + (size_t)(m0 + w*16 + lr)*DIM + lq*8;
    const u16* gB = B + (size_t)(n0 + w*16 + lr)*DIM + lq*8;

#define STG_A(h, ko, bb) do { \
        const u16* _g = gA + (size_t)(h)*32768 + (ko); \
        u16* _l = lds + (bb)*16384 + ((h)*4 + w)*1024; \
        gload16(_g,      _l); \
        gload16(_g + 32, _l + 512); \
    } while(0)
#define STG_B(h, ko, bb) do { \
        const u16* _g = gB + (size_t)(h)*32768 + (ko); \
        u16* _l = lds + (bb)*16384 + 8192 + ((h)*4 + w)*1024; \
        gload16(_g,      _l); \
        gload16(_g + 32, _l + 512); \
    } while(0)

    floatx4 acc[4][4] = {};
    STG_A(0,0,0); STG_A(1,0,0); STG_B(0,0,0); STG_B(1,0,0);

    #pragma unroll 1
    for (int kt=0; kt<8; ++kt){
        const int cur = kt&1, nxt = cur^1;
        const int ko = (kt+1)*64;
        if (kt < 7){
            STG_A(0, ko, nxt);
            asm volatile("s_waitcnt vmcnt(2)" ::: "memory");
        } else {
            asm volatile("s_waitcnt vmcnt(0)" ::: "memory");
        }
        __builtin_amdgcn_s_barrier();
        asm volatile("" ::: "memory");
        const u16* bA = lds + cur*16384 +        wm*4096 + l*8;
        const u16* bB = lds + cur*16384 + 8192 + wn*4096 + l*8;
        short8 af[4][2], bf[2][2];
        // ---- phase 0: read A + B-lo; stage A1; MFMA n-tiles 0,1
        #pragma unroll
        for (int mi=0;mi<4;mi++){
            af[mi][0] = *(const short8*)(bA + mi*1024);
            af[mi][1] = *(const short8*)(bA + mi*1024 + 512);
        }
        #pragma unroll
        for (int ni=0;ni<2;ni++){
            bf[ni][0] = *(const short8*)(bB + ni*1024);
            bf[ni][1] = *(const short8*)(bB + ni*1024 + 512);
        }
        if (kt < 7) STG_A(1, ko, nxt);
        asm volatile("" ::: "memory");
        __builtin_amdgcn_s_barrier();
        __builtin_amdgcn_sched_barrier(0);
        __builtin_amdgcn_s_setprio(1);
        #pragma unroll
        for (int mi=0;mi<4;mi++)
            #pragma unroll
            for (int ni=0;ni<2;ni++){
                acc[mi][ni] = __builtin_amdgcn_mfma_f32_16x16x32_bf16(af[mi][0], bf[ni][0], acc[mi][ni], 0,0,0);
                acc[mi][ni] = __builtin_amdgcn_mfma_f32_16x16x32_bf16(af[mi][1], bf[ni][1], acc[mi][ni], 0,0,0);
            }
        __builtin_amdgcn_s_setprio(0);
        __builtin_amdgcn_sched_barrier(0);
        __builtin_amdgcn_s_barrier();
        // ---- phase 1: read B-hi; stage B0+B1; MFMA n-tiles 2,3
        #pragma unroll
        for (int ni=0;ni<2;ni++){
            bf[ni][0] = *(const short8*)(bB + (2+ni)*1024);
            bf[ni][1] = *(const short8*)(bB + (2+ni)*1024 + 512);
        }
        if (kt < 7){ STG_B(0, ko, nxt); STG_B(1, ko, nxt); }
        asm volatile("" ::: "memory");
        __builtin_amdgcn_s_barrier();
        __builtin_amdgcn_sched_barrier(0);
        __builtin_amdgcn_s_setprio(1);
        #pragma unroll
        for (int mi=0;mi<4;mi++)
            #pragma unroll
            for (int ni=0;ni<2;ni++){
                acc[mi][2+ni] = __builtin_amdgcn_mfma_f32_16x16x32_bf16(af[mi][0], bf[ni][0], acc[mi][2+ni], 0,0,0);
                acc[mi][2+ni] = __builtin_amdgcn_mfma_f32_16x16x32_bf16(af[mi][1], bf[ni][1], acc[mi][2+ni], 0,0,0);
            }
        __builtin_amdgcn_s_setprio(0);
        __builtin_amdgcn_sched_barrier(0);
        asm volatile("" ::: "memory");
        __builtin_amdgcn_s_barrier();
        asm volatile("" ::: "memory");
    }
#undef STG_A
#undef STG_B
    const int isb = *flag;
    const int bat  = m0 / NPIX;
    const int pix0 = (m0 - bat*NPIX) + wm*64;
    float (*ct)[68] = sh.ct[w];
    const u16*   b16 = (const u16*)bias;
    const float* b32 = (const float*)bias;
    const int nl = l>>2, seg = l&3;
    for (int ni=0; ni<4; ni++){
        #pragma unroll
        for (int mi=0;mi<4;mi++)
            #pragma unroll
            for (int r=0;r<4;r++)
                ct[lr][mi*16 + lq*4 + r] = acc[mi][ni][r];   // [n16][pix64]
        int ng = n0 + wn*64 + ni*16 + nl;
        float bv = isb ? b2f(b16[ng]) : b32[ng];
        const float* cp = &ct[nl][seg*16];
        float4 v0 = *(const float4*)(cp);
        float4 v1 = *(const float4*)(cp+4);
        float4 v2 = *(const float4*)(cp+8);
        float4 v3 = *(const float4*)(cp+12);
        v0.x+=bv; v0.y+=bv; v0.z+=bv; v0.w+=bv;
        v1.x+=bv; v1.y+=bv; v1.z+=bv; v1.w+=bv;
        v2.x+=bv; v2.y+=bv; v2.z+=bv; v2.w+=bv;
        v3.x+=bv; v3.y+=bv; v3.z+=bv; v3.w+=bv;
        size_t off = ((size_t)(bat*DIM + ng))*NPIX + pix0 + seg*16;
        if (isb){
            uint4 s0, s1;
            s0.x=pack2(v0.x,v0.y); s0.y=pack2(v0.z,v0.w);
            s0.z=pack2(v1.x,v1.y); s0.w=pack2(v1.z,v1.w);
            s1.x=pack2(v2.x,v2.y); s1.y=pack2(v2.z,v2.w);
            s1.z=pack2(v3.x,v3.y); s1.w=pack2(v3.z,v3.w);
            *(uint4*)((u16*)outv + off)     = s0;
            *(uint4*)((u16*)outv + off + 8) = s1;
        } else {
            float* of = (float*)outv + off;
            *(float4*)(of)    = v0;
            *(float4*)(of+4)  = v1;
            *(float4*)(of+8)  = v2;
            *(float4*)(of+12) = v3;
        }
    }
}

extern "C" void kernel_launch(void* const* d_in, const int* in_sizes, int n_in,
                              void* d_out, int out_size, void* d_ws, size_t ws_size,
                              hipStream_t stream){
    const void* x    = d_in[0];
    const void* wqkv = d_in[1];
    const void* wout = d_in[2];
    const void* bout = d_in[3];
    char* wsb = (char*)d_ws;
    int* flag    = (int*)wsb;                                  // 256 B
    u16* xb      = (u16*)(wsb + 256);                          // [36864][512] bf16
    u16* attn_ws = xb;                                         // alias: xb dead after gemm1
    u16* wqb     = xb + (size_t)M_TOT*DIM;                     // [1536][512]
    u16* wob     = wqb + (size_t)N_QKV*DIM;                    // [512][512]
    u16* qk_ws   = wob + (size_t)DIM*DIM;                      // qkt [3072][12288] (Q,K)
    u16* vt_ws   = qk_ws + (size_t)M_TOT*1024;                 // vtt [3072][6144]
    detect_dtype<<<1, 256, 0, stream>>>((const u16*)wqkv, flag);
    convert_w<<<4096, 256, 0, stream>>>(wqkv, wout, flag, wqb, wob);
    convert_x<<<dim3(144, 8, 4), 256, 0, stream>>>(x, flag, xb);
    gemm_qkv<<<3456, 256, 0, stream>>>(xb, wqb, qk_ws, vt_ws);
    attn_kernel<<<4608, 256, 0, stream>>>(qk_ws, vt_ws, attn_ws);
    gemm_out<<<1152, 256, 0, stream>>>(attn_ws, wob, bout, flag, d_out);
}

// Round 8
// 310.018 us; speedup vs baseline: 1.1446x; 1.1446x over previous
//
#include <hip/hip_runtime.h>

typedef unsigned short u16;
typedef unsigned int u32;
typedef __attribute__((ext_vector_type(8))) short short8;
typedef __attribute__((ext_vector_type(4))) float floatx4;

#define HEADS 8
#define DIM 512          // K for both GEMMs
#define HH 96
#define WW 96
#define NPIX 9216
#define M_TOT 36864
#define N_QKV 1536
#define SCALE 0.125f

__device__ __forceinline__ float b2f(u16 v){
    union{float f;u32 u;}x; x.u=((u32)v)<<16; return x.f;
}
__device__ __forceinline__ u16 f2b(float f){
    union{float f;u32 u;}x; x.f=f;
    u32 u=x.u + 0x7fffu + ((x.u>>16)&1u);
    return (u16)(u>>16);
}
// packed f32x2 -> bf16x2 (RNE, matches f2b bit-for-bit); no builtin on gfx950
__device__ __forceinline__ u32 pack2(float a,float b){
    u32 r; asm("v_cvt_pk_bf16_f32 %0, %1, %2" : "=v"(r) : "v"(a), "v"(b));
    return r;
}
__device__ __forceinline__ short8 mk8(u32 a,u32 b,u32 c,u32 d){
    union{u32 u[4]; short8 v;} x; x.u[0]=a; x.u[1]=b; x.u[2]=c; x.u[3]=d; return x.v;
}

// async global->LDS, 16 B per lane; lds dest = wave-uniform base + lane*16
__device__ __forceinline__ void gload16(const u16* g, u16* l){
    __builtin_amdgcn_global_load_lds(
        (const __attribute__((address_space(1))) u32*)g,
        (__attribute__((address_space(3))) u32*)l, 16, 0, 0);
}

// per-wave dtype self-detect: 256 samples wq[2i] (same criterion as the old
// detect_dtype kernel), wave-uniform result, no LDS/atomics/launch needed.
__device__ __forceinline__ int detect_isb(const u16* wq16, int l){
    int cnt = 0;
    #pragma unroll
    for (int j=0;j<4;j++){
        u16 u = wq16[2*(l*4+j)];
        int e = (u>>7)&0xff;
        cnt += __popcll(__ballot(e>=100 && e<=128));
    }
    return cnt>128;
}

// ---------------------------------------------------------------------------
// Fused converts (one launch, self-detecting):
//  blocks [0,4608): x [b][c][pix] -> xb [b*9216+pix][c] bf16, vectorized
//    (float4 loads, u32 LDS tile [64][33] conflict-free, uint4 stores)
//  blocks [4608,5632): weights -> bf16 (4 elem/thread, float4 -> uint2)
// ---------------------------------------------------------------------------
__global__ __launch_bounds__(256)
void convert_all(const void* __restrict__ xv, const void* __restrict__ wq,
                 const void* __restrict__ wo, u16* __restrict__ xb,
                 u16* __restrict__ wqb, u16* __restrict__ wob){
    const int t = threadIdx.x;
    const int isb = detect_isb((const u16*)wq, t&63);
    const int id = blockIdx.x;
    if (id < 4608){
        __shared__ __align__(16) u32 tu[64][33];
        const int px = id % 144, rem = id/144;
        const int cy = rem & 7, bz = rem >> 3;
        const int p0 = px*64, c0 = cy*64;
        const float* x32 = (const float*)xv;
        const u16*   x16 = (const u16*)xv;
        const int cA = t>>4, pA = (t&15)*4;
        #pragma unroll
        for (int i=0;i<4;i++){
            int cl = cA + i*16;
            size_t s = ((size_t)bz*DIM + c0 + cl)*NPIX + p0 + pA;
            u32 w0, w1;
            if (isb){
                uint2 v = *(const uint2*)(x16 + s);
                w0 = v.x; w1 = v.y;
            } else {
                float4 v = *(const float4*)(x32 + s);
                w0 = pack2(v.x, v.y); w1 = pack2(v.z, v.w);
            }
            tu[cl][(pA>>1)]   = w0;
            tu[cl][(pA>>1)+1] = w1;
        }
        __syncthreads();
        const int pr = t>>2, seg = t&3;
        const int ph = pr>>1, po = pr&1;
        u32 o[8];
        #pragma unroll
        for (int j=0;j<8;j++){
            u32 a = tu[seg*16 + 2*j][ph];
            u32 b = tu[seg*16 + 2*j + 1][ph];
            o[j] = po ? ((a>>16) | (b & 0xffff0000u))
                      : ((a & 0xffffu) | (b<<16));
        }
        u32* dst = (u32*)xb + ((size_t)bz*NPIX + p0 + pr)*256 + (c0>>1) + seg*8;
        *(uint4*)(dst)   = make_uint4(o[0],o[1],o[2],o[3]);
        *(uint4*)(dst+4) = make_uint4(o[4],o[5],o[6],o[7]);
    } else {
        int i4 = (id - 4608)*1024 + t*4;
        const int nq = N_QKV*DIM;                 // 786432
        u32 w0, w1;
        if (i4 < nq){
            if (isb){ uint2 v = *(const uint2*)((const u16*)wq + i4); w0=v.x; w1=v.y; }
            else    { float4 v = *(const float4*)((const float*)wq + i4);
                      w0=pack2(v.x,v.y); w1=pack2(v.z,v.w); }
            *(uint2*)(wqb + i4) = make_uint2(w0,w1);
        } else {
            int j4 = i4 - nq;                     // < 262144
            if (isb){ uint2 v = *(const uint2*)((const u16*)wo + j4); w0=v.x; w1=v.y; }
            else    { float4 v = *(const float4*)((const float*)wo + j4);
                      w0=pack2(v.x,v.y); w1=pack2(v.z,v.w); }
            *(uint2*)(wob + j4) = make_uint2(w0,w1);
        }
    }
}

// ---------------------------------------------------------------------------
// MFMA GEMM 1 (R5-verified, best measured: 88.5us): 256x256, BK=64, 8 waves,
// dbuf, phased. Epilogues write block-contiguous qkt (24KB) / vtt (12KB).
// ---------------------------------------------------------------------------
__global__ __launch_bounds__(512, 2)
void gemm_qkv(const u16* __restrict__ A, const u16* __restrict__ B,
              u16* __restrict__ qkt, u16* __restrict__ vtt){
    __shared__ __align__(16) union ShMem {
        u16 tiles[65536];            // 2 bufs x (A 16384 + B 16384) u16 = 128 KiB
        float ctQ[8][16][68];
        float ctV[8][16][132];
    } sh;
    u16* lds = sh.tiles;
    const int id = blockIdx.x;
    const int xcd = id & 7, slot = id >> 3;        // 864 = 8 x 108
    const int q6 = slot/6;
    const int by = xcd*18 + q6;
    const int bx = slot - q6*6;
    const int t = threadIdx.x;
    const int w = t>>6, l = t&63, lr = l&15, lq = l>>4;
    const int wm2 = w>>2, wn4 = w&3;
    const int m0 = by*256, n0 = bx*256;
    const u16* gA0 = A + (size_t)(m0 +       w*16 + lr)*DIM + lq*8;
    const u16* gA1 = A + (size_t)(m0 + 128 + w*16 + lr)*DIM + lq*8;
    const u16* gB0 = B + (size_t)(n0 +       w*16 + lr)*DIM + lq*8;
    const u16* gB1 = B + (size_t)(n0 + 128 + w*16 + lr)*DIM + lq*8;

#define STG(gp, opb, h, ko, bb) do { \
        const u16* _g = (gp) + (ko); \
        u16* _l = lds + (bb)*32768 + (opb) + ((h)*8 + w)*1024; \
        gload16(_g,      _l); \
        gload16(_g + 32, _l + 512); \
    } while(0)

    floatx4 acc[8][4] = {};
    STG(gA0, 0,     0, 0, 0);
    STG(gA1, 0,     1, 0, 0);
    STG(gB0, 16384, 0, 0, 0);
    STG(gB1, 16384, 1, 0, 0);

    #pragma unroll 1
    for (int ktile=0; ktile<8; ++ktile){
        const int cur = ktile&1, nxt = cur^1;
        const int ko = (ktile+1)*64;
        if (ktile < 7){
            STG(gA0, 0, 0, ko, nxt);
            asm volatile("s_waitcnt vmcnt(2)" ::: "memory");
        } else {
            asm volatile("s_waitcnt vmcnt(0)" ::: "memory");
        }
        __builtin_amdgcn_s_barrier();
        asm volatile("" ::: "memory");
        const u16* bA = lds + cur*32768 +         wm2*8192 + l*8;
        const u16* bB = lds + cur*32768 + 16384 + wn4*4096 + l*8;
        short8 af[4][2], blo[2][2], bhi[2][2];
        // ---- phase 0
        #pragma unroll
        for (int mi=0;mi<4;mi++){
            af[mi][0] = *(const short8*)(bA + mi*1024);
            af[mi][1] = *(const short8*)(bA + mi*1024 + 512);
        }
        #pragma unroll
        for (int ni=0;ni<2;ni++){
            blo[ni][0] = *(const short8*)(bB + ni*1024);
            blo[ni][1] = *(const short8*)(bB + ni*1024 + 512);
        }
        if (ktile < 7) STG(gA1, 0, 1, ko, nxt);
        asm volatile("" ::: "memory");
        __builtin_amdgcn_s_barrier();
        __builtin_amdgcn_sched_barrier(0);
        __builtin_amdgcn_s_setprio(1);
        #pragma unroll
        for (int mi=0;mi<4;mi++)
            #pragma unroll
            for (int ni=0;ni<2;ni++){
                acc[mi][ni] = __builtin_amdgcn_mfma_f32_16x16x32_bf16(af[mi][0], blo[ni][0], acc[mi][ni], 0,0,0);
                acc[mi][ni] = __builtin_amdgcn_mfma_f32_16x16x32_bf16(af[mi][1], blo[ni][1], acc[mi][ni], 0,0,0);
            }
        __builtin_amdgcn_s_setprio(0);
        __builtin_amdgcn_sched_barrier(0);
        __builtin_amdgcn_s_barrier();
        // ---- phase 1
        #pragma unroll
        for (int ni=0;ni<2;ni++){
            bhi[ni][0] = *(const short8*)(bB + (2+ni)*1024);
            bhi[ni][1] = *(const short8*)(bB + (2+ni)*1024 + 512);
        }
        if (ktile < 7) STG(gB0, 16384, 0, ko, nxt);
        asm volatile("" ::: "memory");
        __builtin_amdgcn_s_barrier();
        __builtin_amdgcn_sched_barrier(0);
        __builtin_amdgcn_s_setprio(1);
        #pragma unroll
        for (int mi=0;mi<4;mi++)
            #pragma unroll
            for (int ni=0;ni<2;ni++){
                acc[mi][2+ni] = __builtin_amdgcn_mfma_f32_16x16x32_bf16(af[mi][0], bhi[ni][0], acc[mi][2+ni], 0,0,0);
                acc[mi][2+ni] = __builtin_amdgcn_mfma_f32_16x16x32_bf16(af[mi][1], bhi[ni][1], acc[mi][2+ni], 0,0,0);
            }
        __builtin_amdgcn_s_setprio(0);
        __builtin_amdgcn_sched_barrier(0);
        __builtin_amdgcn_s_barrier();
        // ---- phase 2
        #pragma unroll
        for (int mi=0;mi<4;mi++){
            af[mi][0] = *(const short8*)(bA + (4+mi)*1024);
            af[mi][1] = *(const short8*)(bA + (4+mi)*1024 + 512);
        }
        if (ktile < 7) STG(gB1, 16384, 1, ko, nxt);
        asm volatile("" ::: "memory");
        __builtin_amdgcn_s_barrier();
        __builtin_amdgcn_sched_barrier(0);
        __builtin_amdgcn_s_setprio(1);
        #pragma unroll
        for (int mi=0;mi<4;mi++)
            #pragma unroll
            for (int ni=0;ni<2;ni++){
                acc[4+mi][2+ni] = __builtin_amdgcn_mfma_f32_16x16x32_bf16(af[mi][0], bhi[ni][0], acc[4+mi][2+ni], 0,0,0);
                acc[4+mi][2+ni] = __builtin_amdgcn_mfma_f32_16x16x32_bf16(af[mi][1], bhi[ni][1], acc[4+mi][2+ni], 0,0,0);
            }
        __builtin_amdgcn_s_setprio(0);
        __builtin_amdgcn_sched_barrier(0);
        __builtin_amdgcn_s_barrier();
        // ---- phase 3
        __builtin_amdgcn_s_setprio(1);
        #pragma unroll
        for (int mi=0;mi<4;mi++)
            #pragma unroll
            for (int ni=0;ni<2;ni++){
                acc[4+mi][ni] = __builtin_amdgcn_mfma_f32_16x16x32_bf16(af[mi][0], blo[ni][0], acc[4+mi][ni], 0,0,0);
                acc[4+mi][ni] = __builtin_amdgcn_mfma_f32_16x16x32_bf16(af[mi][1], blo[ni][1], acc[4+mi][ni], 0,0,0);
            }
        __builtin_amdgcn_s_setprio(0);
        __builtin_amdgcn_sched_barrier(0);
        asm volatile("" ::: "memory");
        __builtin_amdgcn_s_barrier();
        asm volatile("" ::: "memory");
    }
#undef STG
    const int bat   = m0 / NPIX;
    const int p0img = (m0 - bat*NPIX) + wm2*128;
    if (bx < 4){
        float (*ct)[68] = sh.ctQ[w];
        const int nbase = n0 + wn4*64;
        const int isK   = (nbase >= 512);
        const int head  = (nbase - (isK ? 512 : 0)) >> 6;
        const int kqoff = isK ? 6144 : 0;
        const size_t blk0 = (size_t)(bat*8 + head)*96;
        #pragma unroll
        for (int mi=0;mi<8;mi++){
            #pragma unroll
            for (int ni=0;ni<4;ni++)
                #pragma unroll
                for (int r=0;r<4;r++)
                    ct[lq*4+r][ni*16+lr] = acc[mi][ni][r];
            int pv  = (p0img + mi*16) >> 4;
            int row = pv/6, mt = pv - row*6;
            u16* dst = qkt + (blk0 + row)*12288 + kqoff + mt*1024 + l*8;
            #pragma unroll
            for (int ks=0;ks<2;ks++){
                const float* cp = &ct[l&15][ks*32 + (l>>4)*8];
                float4 v0 = *(const float4*)(cp);
                float4 v1 = *(const float4*)(cp+4);
                uint4 s;
                s.x=pack2(v0.x,v0.y); s.y=pack2(v0.z,v0.w);
                s.z=pack2(v1.x,v1.y); s.w=pack2(v1.z,v1.w);
                *((uint4*)(dst + ks*512)) = s;
            }
        }
    } else {
        float (*ct)[132] = sh.ctV[w];
        const int head = ((n0 - 1024) + wn4*64) >> 6;
        const size_t blk0 = (size_t)(bat*8 + head)*96;
        for (int ni=0; ni<4; ni++){
            #pragma unroll
            for (int mi=0;mi<8;mi++)
                #pragma unroll
                for (int r=0;r<4;r++)
                    ct[lr][mi*16 + lq*4 + r] = acc[mi][ni][r];
            #pragma unroll
            for (int cc=0;cc<4;cc++){
                int p32 = (p0img + cc*32) >> 5;
                int row = p32/3, jt = p32 - row*3;
                const float* cp = &ct[l&15][cc*32 + (l>>4)*8];
                float4 v0 = *(const float4*)(cp);
                float4 v1 = *(const float4*)(cp+4);
                uint4 s;
                s.x=pack2(v0.x,v0.y); s.y=pack2(v0.z,v0.w);
                s.z=pack2(v1.x,v1.y); s.w=pack2(v1.z,v1.w);
                *((uint4*)(vtt + (blk0 + row)*6144 + (ni*3 + jt)*512 + l*8)) = s;
            }
        }
    }
}

// ---------------------------------------------------------------------------
// Kernel 2 (R5-verified, 33.5us): attention, ONE WAVE per (bh,row,qt).
// Zero LDS, zero barriers. 18432 waves, 4608 blocks, XCD-grouped.
// ---------------------------------------------------------------------------
__global__ __launch_bounds__(256)
void attn_kernel(const u16* __restrict__ qkt, const u16* __restrict__ vtt,
                 u16* __restrict__ attno){
    const int t = threadIdx.x;
    const int w = t>>6, l = t&63, lr = l&15, lq = l>>4;
    const int id  = blockIdx.x;
    const int bid = (id&7)*576 + (id>>3);      // bijective: 4608 = 8*576
    const int widx = bid*4 + w;                // 18432 = 3072 rows * 6 qt
    const int qt   = widx % 6;
    const int rowu = widx / 6;                 // (bat*8+head)*96 + row
    const int row  = rowu % HH;
    const int bh   = rowu / HH;
    const int head = bh & 7, bat = bh >> 3;
    const u16* qkb = qkt + (size_t)rowu*12288;
    const u16* vb  = vtt + (size_t)rowu*6144;
    short8 qf0 = *(const short8*)(qkb + (qt*2+0)*512 + l*8);
    short8 qf1 = *(const short8*)(qkb + (qt*2+1)*512 + l*8);
    floatx4 s[6];
    #pragma unroll
    for (int jt=0;jt<6;jt++){
        short8 k0 = *(const short8*)(qkb + 6144 + (jt*2+0)*512 + l*8);
        short8 k1 = *(const short8*)(qkb + 6144 + (jt*2+1)*512 + l*8);
        floatx4 a = {};
        a = __builtin_amdgcn_mfma_f32_16x16x32_bf16(k0, qf0, a, 0,0,0);
        a = __builtin_amdgcn_mfma_f32_16x16x32_bf16(k1, qf1, a, 0,0,0);
        s[jt] = a;
    }
    float m = -1e30f;
    #pragma unroll
    for (int jt=0;jt<6;jt++)
        #pragma unroll
        for (int r=0;r<4;r++){ s[jt][r] *= SCALE; m = fmaxf(m, s[jt][r]); }
    m = fmaxf(m, __shfl_xor(m, 16));
    m = fmaxf(m, __shfl_xor(m, 32));
    float sum = 0.f;
    u32 pk0[6], pk1[6];
    #pragma unroll
    for (int jt=0;jt<6;jt++){
        float e0 = __expf(s[jt][0]-m), e1 = __expf(s[jt][1]-m);
        float e2 = __expf(s[jt][2]-m), e3 = __expf(s[jt][3]-m);
        sum += e0+e1+e2+e3;
        pk0[jt] = pack2(e0,e1);
        pk1[jt] = pack2(e2,e3);
    }
    sum += __shfl_xor(sum, 16);
    sum += __shfl_xor(sum, 32);
    const float rinv = 1.f/sum;
    const int srcA = lr + ((lq&1)<<5);
    const int srcB = srcA + 16;
    const int hi   = lq>>1;
    short8 pf[3];
    #pragma unroll
    for (int kb=0;kb<3;kb++){
        u32 x0=__shfl(pk0[kb*2],srcA), y0=__shfl(pk0[kb*2+1],srcA);
        u32 x1=__shfl(pk1[kb*2],srcA), y1=__shfl(pk1[kb*2+1],srcA);
        u32 x2=__shfl(pk0[kb*2],srcB), y2=__shfl(pk0[kb*2+1],srcB);
        u32 x3=__shfl(pk1[kb*2],srcB), y3=__shfl(pk1[kb*2+1],srcB);
        pf[kb] = mk8(hi?y0:x0, hi?y1:x1, hi?y2:x2, hi?y3:x3);
    }
    floatx4 o[4] = {};
    #pragma unroll
    for (int kb=0;kb<3;kb++){
        #pragma unroll
        for (int dt=0;dt<4;dt++){
            short8 vf = *(const short8*)(vb + (dt*3+kb)*512 + l*8);
            o[dt] = __builtin_amdgcn_mfma_f32_16x16x32_bf16(vf, pf[kb], o[dt], 0,0,0);
        }
    }
    const size_t pixrow = (size_t)bat*NPIX + row*WW + qt*16;
    u16* ob = attno + (pixrow + lr)*512 + head*64 + lq*4;
    #pragma unroll
    for (int dt=0;dt<4;dt++){
        uint2 st;
        st.x = pack2(o[dt][0]*rinv, o[dt][1]*rinv);
        st.y = pack2(o[dt][2]*rinv, o[dt][3]*rinv);
        *(uint2*)(ob + dt*16) = st;
    }
}

// ---------------------------------------------------------------------------
// MFMA GEMM 2 (R5-verified): out = attn_ws * wob^T + bias. 128x128 tile,
// BK=64, 4 waves, 64 KB LDS -> 2 blocks/CU. Grid 1152 = 8 x 144.
// dtype self-detected per wave (flag kernel removed).
// ---------------------------------------------------------------------------
__global__ __launch_bounds__(256, 2)
void gemm_out(const u16* __restrict__ A, const u16* __restrict__ B,
              const void* __restrict__ wqkv, const void* __restrict__ bias,
              void* __restrict__ outv){
    __shared__ __align__(16) union ShMem {
        u16 tiles[32768];            // 2 bufs x (A 8192 + B 8192) u16 = 64 KiB
        float ct[4][16][68];
    } sh;
    u16* lds = sh.tiles;
    const int id = blockIdx.x;
    const int xcd = id & 7, slot = id >> 3;        // 1152 = 8 x 144
    const int by = xcd*36 + (slot>>2);
    const int bx = slot & 3;
    const int t = threadIdx.x;
    const int w = t>>6, l = t&63, lr = l&15, lq = l>>4;
    const int isb = detect_isb((const u16*)wqkv, l);
    const int wm = w>>1, wn = w&1;                 // wave = 64(M) x 64(N)
    const int m0 = by*128, n0 = bx*128;
    const u16* gA = A + (size_t)(m0 + w*16 + lr)*DIM + lq*8;
    const u16* gB = B + (size_t)(n0 + w*16 + lr)*DIM + lq*8;

#define STG_A(h, ko, bb) do { \
        const u16* _g = gA + (size_t)(h)*32768 + (ko); \
        u16* _l = lds + (bb)*16384 + ((h)*4 + w)*1024; \
        gload16(_g,      _l); \
        gload16(_g + 32, _l + 512); \
    } while(0)
#define STG_B(h, ko, bb) do { \
        const u16* _g = gB + (size_t)(h)*32768 + (ko); \
        u16* _l = lds + (bb)*16384 + 8192 + ((h)*4 + w)*1024; \
        gload16(_g,      _l); \
        gload16(_g + 32, _l + 512); \
    } while(0)

    floatx4 acc[4][4] = {};
    STG_A(0,0,0); STG_A(1,0,0); STG_B(0,0,0); STG_B(1,0,0);

    #pragma unroll 1
    for (int kt=0; kt<8; ++kt){
        const int cur = kt&1, nxt = cur^1;
        const int ko = (kt+1)*64;
        if (kt < 7){
            STG_A(0, ko, nxt);
            asm volatile("s_waitcnt vmcnt(2)" ::: "memory");
        } else {
            asm volatile("s_waitcnt vmcnt(0)" ::: "memory");
        }
        __builtin_amdgcn_s_barrier();
        asm volatile("" ::: "memory");
        const u16* bA = lds + cur*16384 +        wm*4096 + l*8;
        const u16* bB = lds + cur*16384 + 8192 + wn*4096 + l*8;
        short8 af[4][2], bf[2][2];
        // ---- phase 0: read A + B-lo; stage A1; MFMA n-tiles 0,1
        #pragma unroll
        for (int mi=0;mi<4;mi++){
            af[mi][0] = *(const short8*)(bA + mi*1024);
            af[mi][1] = *(const short8*)(bA + mi*1024 + 512);
        }
        #pragma unroll
        for (int ni=0;ni<2;ni++){
            bf[ni][0] = *(const short8*)(bB + ni*1024);
            bf[ni][1] = *(const short8*)(bB + ni*1024 + 512);
        }
        if (kt < 7) STG_A(1, ko, nxt);
        asm volatile("" ::: "memory");
        __builtin_amdgcn_s_barrier();
        __builtin_amdgcn_sched_barrier(0);
        __builtin_amdgcn_s_setprio(1);
        #pragma unroll
        for (int mi=0;mi<4;mi++)
            #pragma unroll
            for (int ni=0;ni<2;ni++){
                acc[mi][ni] = __builtin_amdgcn_mfma_f32_16x16x32_bf16(af[mi][0], bf[ni][0], acc[mi][ni], 0,0,0);
                acc[mi][ni] = __builtin_amdgcn_mfma_f32_16x16x32_bf16(af[mi][1], bf[ni][1], acc[mi][ni], 0,0,0);
            }
        __builtin_amdgcn_s_setprio(0);
        __builtin_amdgcn_sched_barrier(0);
        __builtin_amdgcn_s_barrier();
        // ---- phase 1: read B-hi; stage B0+B1; MFMA n-tiles 2,3
        #pragma unroll
        for (int ni=0;ni<2;ni++){
            bf[ni][0] = *(const short8*)(bB + (2+ni)*1024);
            bf[ni][1] = *(const short8*)(bB + (2+ni)*1024 + 512);
        }
        if (kt < 7){ STG_B(0, ko, nxt); STG_B(1, ko, nxt); }
        asm volatile("" ::: "memory");
        __builtin_amdgcn_s_barrier();
        __builtin_amdgcn_sched_barrier(0);
        __builtin_amdgcn_s_setprio(1);
        #pragma unroll
        for (int mi=0;mi<4;mi++)
            #pragma unroll
            for (int ni=0;ni<2;ni++){
                acc[mi][2+ni] = __builtin_amdgcn_mfma_f32_16x16x32_bf16(af[mi][0], bf[ni][0], acc[mi][2+ni], 0,0,0);
                acc[mi][2+ni] = __builtin_amdgcn_mfma_f32_16x16x32_bf16(af[mi][1], bf[ni][1], acc[mi][2+ni], 0,0,0);
            }
        __builtin_amdgcn_s_setprio(0);
        __builtin_amdgcn_sched_barrier(0);
        asm volatile("" ::: "memory");
        __builtin_amdgcn_s_barrier();
        asm volatile("" ::: "memory");
    }
#undef STG_A
#undef STG_B
    const int bat  = m0 / NPIX;
    const int pix0 = (m0 - bat*NPIX) + wm*64;
    float (*ct)[68] = sh.ct[w];
    const u16*   b16 = (const u16*)bias;
    const float* b32 = (const float*)bias;
    const int nl = l>>2, seg = l&3;
    for (int ni=0; ni<4; ni++){
        #pragma unroll
        for (int mi=0;mi<4;mi++)
            #pragma unroll
            for (int r=0;r<4;r++)
                ct[lr][mi*16 + lq*4 + r] = acc[mi][ni][r];   // [n16][pix64]
        int ng = n0 + wn*64 + ni*16 + nl;
        float bv = isb ? b2f(b16[ng]) : b32[ng];
        const float* cp = &ct[nl][seg*16];
        float4 v0 = *(const float4*)(cp);
        float4 v1 = *(const float4*)(cp+4);
        float4 v2 = *(const float4*)(cp+8);
        float4 v3 = *(const float4*)(cp+12);
        v0.x+=bv; v0.y+=bv; v0.z+=bv; v0.w+=bv;
        v1.x+=bv; v1.y+=bv; v1.z+=bv; v1.w+=bv;
        v2.x+=bv; v2.y+=bv; v2.z+=bv; v2.w+=bv;
        v3.x+=bv; v3.y+=bv; v3.z+=bv; v3.w+=bv;
        size_t off = ((size_t)(bat*DIM + ng))*NPIX + pix0 + seg*16;
        if (isb){
            uint4 s0, s1;
            s0.x=pack2(v0.x,v0.y); s0.y=pack2(v0.z,v0.w);
            s0.z=pack2(v1.x,v1.y); s0.w=pack2(v1.z,v1.w);
            s1.x=pack2(v2.x,v2.y); s1.y=pack2(v2.z,v2.w);
            s1.z=pack2(v3.x,v3.y); s1.w=pack2(v3.z,v3.w);
            *(uint4*)((u16*)outv + off)     = s0;
            *(uint4*)((u16*)outv + off + 8) = s1;
        } else {
            float* of = (float*)outv + off;
            *(float4*)(of)    = v0;
            *(float4*)(of+4)  = v1;
            *(float4*)(of+8)  = v2;
            *(float4*)(of+12) = v3;
        }
    }
}

extern "C" void kernel_launch(void* const* d_in, const int* in_sizes, int n_in,
                              void* d_out, int out_size, void* d_ws, size_t ws_size,
                              hipStream_t stream){
    const void* x    = d_in[0];
    const void* wqkv = d_in[1];
    const void* wout = d_in[2];
    const void* bout = d_in[3];
    char* wsb = (char*)d_ws;
    u16* xb      = (u16*)(wsb + 256);                          // [36864][512] bf16
    u16* attn_ws = xb;                                         // alias: xb dead after gemm1
    u16* wqb     = xb + (size_t)M_TOT*DIM;                     // [1536][512]
    u16* wob     = wqb + (size_t)N_QKV*DIM;                    // [512][512]
    u16* qk_ws   = wob + (size_t)DIM*DIM;                      // qkt [3072][12288] (Q,K)
    u16* vt_ws   = qk_ws + (size_t)M_TOT*1024;                 // vtt [3072][6144]
    convert_all<<<5632, 256, 0, stream>>>(x, wqkv, wout, xb, wqb, wob);
    gemm_qkv<<<864, 512, 0, stream>>>(xb, wqb, qk_ws, vt_ws);
    attn_kernel<<<4608, 256, 0, stream>>>(qk_ws, vt_ws, attn_ws);
    gemm_out<<<1152, 256, 0, stream>>>(attn_ws, wob, wqkv, bout, d_out);
}